// Round 1
// baseline (129.496 us; speedup 1.0000x reference)
//
#include <hip/hip_runtime.h>
#include <cstdint>
#include <cstddef>

// Problem constants
#define FF 64
#define EE 64
#define HH 8
#define PP 512
#define MM 16384   // B*T = 64*256
#define KK 1024    // 2 * F * H  (both branches concatenated)
#define BM 128     // gemm m-tile
#define BN 256     // gemm n-tile

typedef __bf16 bf16x8 __attribute__((ext_vector_type(8)));
typedef float  floatx4 __attribute__((ext_vector_type(4)));

// float -> bf16 (RNE)
__device__ __forceinline__ unsigned short f2bf(float f) {
    unsigned int u = __float_as_uint(f);
    u += 0x7FFFu + ((u >> 16) & 1u);
    return (unsigned short)(u >> 16);
}

__device__ __forceinline__ unsigned pack2(unsigned short a, unsigned short b) {
    return (unsigned)a | ((unsigned)b << 16);
}

// tanh from pre-scaled arg t = (val*w+b)*2*log2e:  1 - 2/(exp2(t)+1)
// (the 2*log2e factor is folded into the LDS-staged w1/b1)
__device__ __forceinline__ float fast_tanh_s(float t) {
    float e, r;
    asm("v_exp_f32 %0, %1" : "=v"(e) : "v"(t));
    float d = e + 1.0f;
    asm("v_rcp_f32 %0, %1" : "=v"(r) : "v"(d));
    return __builtin_fmaf(-2.0f, r, 1.0f);
}

// async global->LDS, 16B per lane; LDS dest = wave-uniform base + lane*16
__device__ __forceinline__ void gl_lds16(const unsigned short* g, unsigned short* s) {
    __builtin_amdgcn_global_load_lds(
        (__attribute__((address_space(1))) void*)(void*)g,
        (__attribute__((address_space(3))) void*)s,
        16, 0, 0);
}

// ---------------------------------------------------------------------------
// Phase 1: BmatT[n][k] (bf16, k-contiguous), k = br*512 + f*8 + h
//   BmatT[n][br,f,h] = sum_e w2[f,h,e] * W[(f*64+e)*512 + n]
// (unchanged from previous round)
// ---------------------------------------------------------------------------
__global__ __launch_bounds__(256) void combine_kernel(
    const float* __restrict__ w2v, const float* __restrict__ w2t,
    const float* __restrict__ wx,  const float* __restrict__ wt,
    unsigned short* __restrict__ BmatT)
{
    const int tid = threadIdx.x;
    const int bid = blockIdx.x;
    const int br = bid >> 7;
    const int f  = (bid >> 1) & 63;
    const int nh = bid & 1;
    const float* __restrict__ w2 = br ? w2t : w2v;   // [F][H][E]
    const float* __restrict__ W  = br ? wt  : wx;    // [F*E][P]
    __shared__ float w2s[HH * EE];
    for (int i = tid; i < HH * EE; i += 256) w2s[i] = w2[f * HH * EE + i];
    __syncthreads();
    const int n = nh * 256 + tid;
    float acc[HH] = {0,0,0,0,0,0,0,0};
    const float* Wcol = W + (size_t)f * EE * PP + n;
    #pragma unroll 8
    for (int e = 0; e < EE; ++e) {
        const float wv = Wcol[(size_t)e * PP];
        #pragma unroll
        for (int h = 0; h < HH; ++h)
            acc[h] = __builtin_fmaf(w2s[h * EE + e], wv, acc[h]);
    }
    uint4 v;
    v.x = pack2(f2bf(acc[0]), f2bf(acc[1]));
    v.y = pack2(f2bf(acc[2]), f2bf(acc[3]));
    v.z = pack2(f2bf(acc[4]), f2bf(acc[5]));
    v.w = pack2(f2bf(acc[6]), f2bf(acc[7]));
    *reinterpret_cast<uint4*>(&BmatT[(size_t)n * KK + br * 512 + f * 8]) = v;
}

// ---------------------------------------------------------------------------
// Phase 2: fused featurize + GEMM.
//   out[m][n] = sum_k A[m][k]*BmatT[n][k] + bx[n] + bt[n]
//   A[m][br*512+f*8+h] = tanh(in_br[m][f]*w1[f][h]+b1[f][h])  in-tile.
//
// Restructure vs previous round: the old 64x256/2-block/2-barrier shape was
// LDS-BW-bound (~1150 bank-cy/iter, frag reads 768 of it: wave tiles 32x64
// gave B only 2x reuse). New shape:
//   - BM=128 x BN=256, 8 waves each owning a 64x64 sub-tile (acc 4x4):
//     A and B fragments both reused 4x -> LDS frag traffic/FLOP -33%,
//     B L2 traffic halved (128 m-rows share one B staging).
//   - LDS 104 KB: double-buffered As(2x16K)+Bs(2x32K)+w1/b1(8K) -> 1 block/CU.
//   - Single barrier per k-iter: body = {DMA B(i+1) -> buf^1, prefetch
//     x/time vals(i+1), MFMA on buf, tanh A(i+1) -> buf^1, barrier}.
//     VALU (tanh) overlaps the MFMA pipe within/between the 2 waves/SIMD.
//   - Same XOR chunk swizzle on As/Bs (conflict-free, proven pattern).
//   - grid (128,2): ids x and x+128 == x mod 8 -> same XCD -> x/time L2 reuse.
// ---------------------------------------------------------------------------
__global__ __launch_bounds__(512, 2) void gemm_fused_kernel(
    const float* __restrict__ x,   const float* __restrict__ tmv,
    const float* __restrict__ w1v, const float* __restrict__ b1v,
    const float* __restrict__ w1t, const float* __restrict__ b1t,
    const unsigned short* __restrict__ Bt,  // BmatT [PP][KK]
    const float* __restrict__ bx, const float* __restrict__ bt,
    float* __restrict__ out)                 // [MM][PP]
{
    __shared__ __align__(16) unsigned short As[2][BM * 64];   // 2 x 16 KB
    __shared__ __align__(16) unsigned short Bs[2][BN * 64];   // 2 x 32 KB
    __shared__ __align__(16) float w1s[2 * FF * HH];          // 4 KB (pre-scaled)
    __shared__ __align__(16) float b1s[2 * FF * HH];          // 4 KB (pre-scaled)

    const int tid  = threadIdx.x;
    const int wave = tid >> 6;
    const int lane = tid & 63;
    const int m0 = blockIdx.x * BM;
    const int n0 = blockIdx.y * BN;

    // stage w1/b1 scaled by 2*log2e (folds the mul out of every tanh)
    {
        const float c = 2.8853900817779268f;
        #pragma unroll
        for (int t = 0; t < 2; ++t) {
            const int idx = tid + t * 512;
            const int br  = idx >> 9;
            const int rem = idx & 511;
            w1s[idx] = (br ? w1t : w1v)[rem] * c;
            b1s[idx] = (br ? b1t : b1v)[rem] * c;
        }
    }
    __syncthreads();

    const int wm  = wave >> 2;             // 0..1  (m half, 64 rows)
    const int wn  = wave & 3;              // 0..3  (n quadrant, 64 cols)
    const int q   = lane >> 4;
    const int ml  = lane & 15;
    const int mlx = ml & 7;
    const int lr  = lane >> 3;             // 0..7 row within 8-row segment
    const int lkg = ((lane & 7) ^ lr) * 8; // swizzled global k-offset (shorts)
    const int fi  = tid & 7;               // feature sub-index for A-compute
    const int arow = tid >> 3;             // 0..63: A rows arow, arow+64
    const int pchunk = (fi ^ (arow & 7)) * 8;   // same for arow+64 (bit3 untouched)

    floatx4 acc[4][4];
    #pragma unroll
    for (int i = 0; i < 4; ++i)
        #pragma unroll
        for (int j = 0; j < 4; ++j)
            acc[i][j] = (floatx4){0.f, 0.f, 0.f, 0.f};

    // tanh-compute of one (f, 2-rows) chunk pair into As[buf]
    auto computeA = [&](int buf, int br, int f, float v0, float v1) {
        const float4 wlo = reinterpret_cast<const float4*>(w1s)[br * 128 + f * 2];
        const float4 whi = reinterpret_cast<const float4*>(w1s)[br * 128 + f * 2 + 1];
        const float4 blo = reinterpret_cast<const float4*>(b1s)[br * 128 + f * 2];
        const float4 bhi = reinterpret_cast<const float4*>(b1s)[br * 128 + f * 2 + 1];
        bf16x8 o0, o1;
        o0[0] = (__bf16)fast_tanh_s(__builtin_fmaf(v0, wlo.x, blo.x));
        o0[1] = (__bf16)fast_tanh_s(__builtin_fmaf(v0, wlo.y, blo.y));
        o0[2] = (__bf16)fast_tanh_s(__builtin_fmaf(v0, wlo.z, blo.z));
        o0[3] = (__bf16)fast_tanh_s(__builtin_fmaf(v0, wlo.w, blo.w));
        o0[4] = (__bf16)fast_tanh_s(__builtin_fmaf(v0, whi.x, bhi.x));
        o0[5] = (__bf16)fast_tanh_s(__builtin_fmaf(v0, whi.y, bhi.y));
        o0[6] = (__bf16)fast_tanh_s(__builtin_fmaf(v0, whi.z, bhi.z));
        o0[7] = (__bf16)fast_tanh_s(__builtin_fmaf(v0, whi.w, bhi.w));
        o1[0] = (__bf16)fast_tanh_s(__builtin_fmaf(v1, wlo.x, blo.x));
        o1[1] = (__bf16)fast_tanh_s(__builtin_fmaf(v1, wlo.y, blo.y));
        o1[2] = (__bf16)fast_tanh_s(__builtin_fmaf(v1, wlo.z, blo.z));
        o1[3] = (__bf16)fast_tanh_s(__builtin_fmaf(v1, wlo.w, blo.w));
        o1[4] = (__bf16)fast_tanh_s(__builtin_fmaf(v1, whi.x, bhi.x));
        o1[5] = (__bf16)fast_tanh_s(__builtin_fmaf(v1, whi.y, bhi.y));
        o1[6] = (__bf16)fast_tanh_s(__builtin_fmaf(v1, whi.z, bhi.z));
        o1[7] = (__bf16)fast_tanh_s(__builtin_fmaf(v1, whi.w, bhi.w));
        *reinterpret_cast<bf16x8*>(&As[buf][arow * 64 + pchunk])        = o0;
        *reinterpret_cast<bf16x8*>(&As[buf][(arow + 64) * 64 + pchunk]) = o1;
    };

    // ---- prologue: fill buffer 0 (k0 = 0, branch 0, f = fi) ----
    {
        #pragma unroll
        for (int j = 0; j < 4; ++j) {
            const int seg = wave * 4 + j;    // 0..31, 8 rows each
            gl_lds16(&Bt[(size_t)(n0 + seg * 8 + lr) * KK + lkg], &Bs[0][seg * 512]);
        }
        const float v0 = x[(size_t)(m0 + arow) * FF + fi];
        const float v1 = x[(size_t)(m0 + arow + 64) * FF + fi];
        computeA(0, 0, fi, v0, v1);
    }
    __syncthreads();   // buffer 0 ready (vmcnt+lgkm drained by syncthreads)

    // ---- main loop: 16 k-iters, one barrier each ----
    #pragma unroll 2
    for (int i = 0; i < 16; ++i) {
        const int cur = i & 1;
        float nv0 = 0.f, nv1 = 0.f;

        if (i < 15) {
            const int in  = i + 1;
            const int k0n = in * 64;
            // issue next B-tile DMA first (hides L2 latency under MFMA+tanh)
            #pragma unroll
            for (int j = 0; j < 4; ++j) {
                const int seg = wave * 4 + j;
                gl_lds16(&Bt[(size_t)(n0 + seg * 8 + lr) * KK + k0n + lkg],
                         &Bs[cur ^ 1][seg * 512]);
            }
            // prefetch next x/time vals into registers
            const float* __restrict__ inp = (in & 8) ? tmv : x;
            const int fn = ((in & 7) << 3) + fi;
            nv0 = inp[(size_t)(m0 + arow) * FF + fn];
            nv1 = inp[(size_t)(m0 + arow + 64) * FF + fn];
        }

        // ---- MFMA on current buffer ----
        #pragma unroll
        for (int kk = 0; kk < 64; kk += 32) {
            const int cl = (kk >> 3) + q;          // logical chunk 0..7
            const int co = (cl ^ mlx) * 8;          // swizzled offset (shorts)
            bf16x8 af[4], bfr[4];
            #pragma unroll
            for (int mt = 0; mt < 4; ++mt)
                af[mt] = *reinterpret_cast<const bf16x8*>(
                    &As[cur][(wm * 64 + mt * 16 + ml) * 64 + co]);
            #pragma unroll
            for (int nt = 0; nt < 4; ++nt)
                bfr[nt] = *reinterpret_cast<const bf16x8*>(
                    &Bs[cur][(wn * 64 + nt * 16 + ml) * 64 + co]);
            #pragma unroll
            for (int mt = 0; mt < 4; ++mt)
                #pragma unroll
                for (int nt = 0; nt < 4; ++nt)
                    acc[mt][nt] = __builtin_amdgcn_mfma_f32_16x16x32_bf16(
                        af[mt], bfr[nt], acc[mt][nt], 0, 0, 0);
        }

        // ---- tanh for next buffer (VALU; overlaps MFMA pipe) ----
        if (i < 15) {
            const int in = i + 1;
            computeA(cur ^ 1, in >> 3, ((in & 7) << 3) + fi, nv0, nv1);
        }
        __syncthreads();
    }

    // epilogue: nt innermost -> 4 consecutive 64B chunks per output row
    float bias[4];
    #pragma unroll
    for (int nt = 0; nt < 4; ++nt) {
        const int n = n0 + wn * 64 + nt * 16 + ml;
        bias[nt] = bx[n] + bt[n];
    }
    #pragma unroll
    for (int mt = 0; mt < 4; ++mt) {
        const int mb = m0 + wm * 64 + mt * 16 + q * 4;
        #pragma unroll
        for (int r = 0; r < 4; ++r) {
            float* orow = out + (size_t)(mb + r) * PP + n0 + wn * 64 + ml;
            #pragma unroll
            for (int nt = 0; nt < 4; ++nt)
                orow[nt * 16] = acc[mt][nt][r] + bias[nt];
        }
    }
}

// ---------------------------------------------------------------------------
extern "C" void kernel_launch(void* const* d_in, const int* in_sizes, int n_in,
                              void* d_out, int out_size, void* d_ws, size_t ws_size,
                              hipStream_t stream)
{
    const float* x   = (const float*)d_in[0];
    const float* tmv = (const float*)d_in[1];
    const float* w1v = (const float*)d_in[2];
    const float* b1v = (const float*)d_in[3];
    const float* w2v = (const float*)d_in[4];
    const float* w1t = (const float*)d_in[5];
    const float* b1t = (const float*)d_in[6];
    const float* w2t = (const float*)d_in[7];
    const float* wx  = (const float*)d_in[8];
    const float* bx  = (const float*)d_in[9];
    const float* wt  = (const float*)d_in[10];
    const float* bt  = (const float*)d_in[11];
    float* out = (float*)d_out;

    // ws: [0,1MB) BmatT bf16 [512][1024]
    unsigned short* Bws = (unsigned short*)d_ws;

    combine_kernel<<<256, 256, 0, stream>>>(w2v, w2t, wx, wt, Bws);
    gemm_fused_kernel<<<dim3(MM / BM, PP / BN), 512, 0, stream>>>(
        x, tmv, w1v, b1v, w1t, b1t, Bws, bx, bt, out);
}

// Round 2
// 126.054 us; speedup vs baseline: 1.0273x; 1.0273x over previous
//
#include <hip/hip_runtime.h>
#include <cstdint>
#include <cstddef>

// Problem constants
#define FF 64
#define EE 64
#define HH 8
#define PP 512
#define MM 16384   // B*T = 64*256
#define KK 1024    // 2 * F * H  (both branches concatenated)

typedef __bf16 bf16x8 __attribute__((ext_vector_type(8)));
typedef float  floatx4 __attribute__((ext_vector_type(4)));

// float -> bf16 (RNE)
__device__ __forceinline__ unsigned short f2bf(float f) {
    unsigned int u = __float_as_uint(f);
    u += 0x7FFFu + ((u >> 16) & 1u);
    return (unsigned short)(u >> 16);
}

__device__ __forceinline__ unsigned pack2(unsigned short a, unsigned short b) {
    return (unsigned)a | ((unsigned)b << 16);
}

// tanh from pre-scaled arg t = (val*w+b)*2*log2e:  1 - 2/(exp2(t)+1)
// (the 2*log2e factor is folded into the LDS-staged w1/b1)
__device__ __forceinline__ float fast_tanh_s(float t) {
    float e, r;
    asm("v_exp_f32 %0, %1" : "=v"(e) : "v"(t));
    float d = e + 1.0f;
    asm("v_rcp_f32 %0, %1" : "=v"(r) : "v"(d));
    return __builtin_fmaf(-2.0f, r, 1.0f);
}

// async global->LDS, 16B per lane; LDS dest = wave-uniform base + lane*16
__device__ __forceinline__ void gl_lds16(const unsigned short* g, unsigned short* s) {
    __builtin_amdgcn_global_load_lds(
        (__attribute__((address_space(1))) void*)(void*)g,
        (__attribute__((address_space(3))) void*)s,
        16, 0, 0);
}

// ---------------------------------------------------------------------------
// Phase 1: BmatT[n][k] (bf16, k-contiguous), k = br*512 + f*8 + h
//   BmatT[n][br,f,h] = sum_e w2[f,h,e] * W[(f*64+e)*512 + n]
// (unchanged — verified at 125.3 us baseline)
// ---------------------------------------------------------------------------
__global__ __launch_bounds__(256) void combine_kernel(
    const float* __restrict__ w2v, const float* __restrict__ w2t,
    const float* __restrict__ wx,  const float* __restrict__ wt,
    unsigned short* __restrict__ BmatT)
{
    const int tid = threadIdx.x;
    const int bid = blockIdx.x;
    const int br = bid >> 7;
    const int f  = (bid >> 1) & 63;
    const int nh = bid & 1;
    const float* __restrict__ w2 = br ? w2t : w2v;   // [F][H][E]
    const float* __restrict__ W  = br ? wt  : wx;    // [F*E][P]
    __shared__ float w2s[HH * EE];
    for (int i = tid; i < HH * EE; i += 256) w2s[i] = w2[f * HH * EE + i];
    __syncthreads();
    const int n = nh * 256 + tid;
    float acc[HH] = {0,0,0,0,0,0,0,0};
    const float* Wcol = W + (size_t)f * EE * PP + n;
    #pragma unroll 8
    for (int e = 0; e < EE; ++e) {
        const float wv = Wcol[(size_t)e * PP];
        #pragma unroll
        for (int h = 0; h < HH; ++h)
            acc[h] = __builtin_fmaf(w2s[h * EE + e], wv, acc[h]);
    }
    uint4 v;
    v.x = pack2(f2bf(acc[0]), f2bf(acc[1]));
    v.y = pack2(f2bf(acc[2]), f2bf(acc[3]));
    v.z = pack2(f2bf(acc[4]), f2bf(acc[5]));
    v.w = pack2(f2bf(acc[6]), f2bf(acc[7]));
    *reinterpret_cast<uint4*>(&BmatT[(size_t)n * KK + br * 512 + f * 8]) = v;
}

// ---------------------------------------------------------------------------
// Phase 2: fused featurize + GEMM  (round-0 verified structure, reverted).
//   out[m][n] = sum_k A[m][k]*BmatT[n][k] + bx[n] + bt[n]
//   A[m][br*512+f*8+h] = tanh(in_br[m][f]*w1[f][h]+b1[f][h])  in-tile.
// 512 threads (8 waves), tile 64m x 256n, BK=64, 2 blocks/CU co-resident
// (the co-residency provides the phase overlap: block A in MFMA phase while
//  block B is in tanh/DMA phase — round-1's 1-block/CU dbuf lost this, -4us).
// ONE change vs round-0: the per-iter x/time scalar load is software-
// pipelined one iteration ahead (issued during the MFMA phase, where its
// ~200-300cy latency hides under MFMA+LDS work instead of sitting on the
// phase-1 critical path before the tanh chain). +1 VGPR, no sync change.
// ---------------------------------------------------------------------------
__global__ __launch_bounds__(512, 4) void gemm_fused_kernel(
    const float* __restrict__ x,   const float* __restrict__ tmv,
    const float* __restrict__ w1v, const float* __restrict__ b1v,
    const float* __restrict__ w1t, const float* __restrict__ b1t,
    const unsigned short* __restrict__ Bt,  // BmatT [PP][KK]
    const float* __restrict__ bx, const float* __restrict__ bt,
    float* __restrict__ out)                 // [MM][PP]
{
    __shared__ __align__(16) unsigned short As[64 * 64];    // 8 KB
    __shared__ __align__(16) unsigned short Bs[256 * 64];   // 32 KB
    __shared__ __align__(16) float w1s[2 * FF * HH];        // 4 KB (pre-scaled)
    __shared__ __align__(16) float b1s[2 * FF * HH];        // 4 KB (pre-scaled)

    const int tid  = threadIdx.x;
    const int wave = tid >> 6;
    const int lane = tid & 63;
    const int m0 = blockIdx.x * 64;
    const int n0 = blockIdx.y * 256;

    // stage w1/b1 scaled by 2*log2e (folds the mul out of every tanh)
    {
        const float c = 2.8853900817779268f;
        #pragma unroll
        for (int t = 0; t < 2; ++t) {
            const int idx = tid + t * 512;
            const int br  = idx >> 9;
            const int rem = idx & 511;
            w1s[idx] = (br ? w1t : w1v)[rem] * c;
            b1s[idx] = (br ? b1t : b1v)[rem] * c;
        }
    }
    __syncthreads();

    const int wm  = wave >> 2;             // 0..1  (m quadrant, 32 rows)
    const int wn  = wave & 3;              // 0..3  (n quadrant, 64 cols)
    const int q   = lane >> 4;
    const int ml  = lane & 15;
    const int mlx = ml & 7;
    const int lr  = lane >> 3;             // 0..7 row within 8-row segment
    const int lkg = ((lane & 7) ^ lr) * 8; // swizzled global k-offset (shorts)
    const int fi  = tid & 7;               // feature sub-index for A-compute
    const int arow = tid >> 3;             // 0..63: A row this thread computes
    const int pchunk = (fi ^ (arow & 7)) * 8;

    floatx4 acc[2][4];
    #pragma unroll
    for (int i = 0; i < 2; ++i)
        #pragma unroll
        for (int j = 0; j < 4; ++j)
            acc[i][j] = (floatx4){0.f, 0.f, 0.f, 0.f};

    // software-pipelined input value: vcur feeds iter i's tanh; the load for
    // iter i+1 is issued during iter i's MFMA phase.
    float vcur = x[(size_t)(m0 + arow) * FF + fi];
    float vnext = 0.f;

    for (int i = 0; i < 16; ++i) {
        const int k0 = i * 64;
        const int br = i >> 3;

        // ---- B staging (DMA overlaps the tanh VALU below) ----
        #pragma unroll
        for (int j = 0; j < 4; ++j) {
            const int seg = wave * 4 + j;        // 0..31
            gl_lds16(&Bt[(size_t)(n0 + seg * 8 + lr) * KK + k0 + lkg], &Bs[seg * 512]);
        }

        // ---- A tile: one (row, f) chunk of 8 tanh per thread (from vcur) ----
        {
            const int f = ((i & 7) << 3) + fi;
            const float val = vcur;
            const float4 wlo = reinterpret_cast<const float4*>(w1s)[br * 128 + f * 2];
            const float4 whi = reinterpret_cast<const float4*>(w1s)[br * 128 + f * 2 + 1];
            const float4 blo = reinterpret_cast<const float4*>(b1s)[br * 128 + f * 2];
            const float4 bhi = reinterpret_cast<const float4*>(b1s)[br * 128 + f * 2 + 1];
            float hv[8];
            hv[0] = fast_tanh_s(__builtin_fmaf(val, wlo.x, blo.x));
            hv[1] = fast_tanh_s(__builtin_fmaf(val, wlo.y, blo.y));
            hv[2] = fast_tanh_s(__builtin_fmaf(val, wlo.z, blo.z));
            hv[3] = fast_tanh_s(__builtin_fmaf(val, wlo.w, blo.w));
            hv[4] = fast_tanh_s(__builtin_fmaf(val, whi.x, bhi.x));
            hv[5] = fast_tanh_s(__builtin_fmaf(val, whi.y, bhi.y));
            hv[6] = fast_tanh_s(__builtin_fmaf(val, whi.z, bhi.z));
            hv[7] = fast_tanh_s(__builtin_fmaf(val, whi.w, bhi.w));
            uint4 v;
            v.x = pack2(f2bf(hv[0]), f2bf(hv[1]));
            v.y = pack2(f2bf(hv[2]), f2bf(hv[3]));
            v.z = pack2(f2bf(hv[4]), f2bf(hv[5]));
            v.w = pack2(f2bf(hv[6]), f2bf(hv[7]));
            *reinterpret_cast<uint4*>(&As[arow * 64 + pchunk]) = v;
        }
        __syncthreads();   // As writes + Bs DMA visible

        // ---- prefetch next iter's input value (hides under MFMA below) ----
        if (i < 15) {
            const int in = i + 1;
            const float* __restrict__ inp = (in & 8) ? tmv : x;
            vnext = inp[(size_t)(m0 + arow) * FF + ((in & 7) << 3) + fi];
        }

        #pragma unroll
        for (int kk = 0; kk < 64; kk += 32) {
            const int cl = (kk >> 3) + q;          // logical chunk 0..7
            const int co = (cl ^ mlx) * 8;          // swizzled offset (shorts)
            bf16x8 af[2], bfr[4];
            #pragma unroll
            for (int mt = 0; mt < 2; ++mt)
                af[mt] = *reinterpret_cast<const bf16x8*>(
                    &As[(wm * 32 + mt * 16 + ml) * 64 + co]);
            #pragma unroll
            for (int nt = 0; nt < 4; ++nt)
                bfr[nt] = *reinterpret_cast<const bf16x8*>(
                    &Bs[(wn * 64 + nt * 16 + ml) * 64 + co]);
            #pragma unroll
            for (int mt = 0; mt < 2; ++mt)
                #pragma unroll
                for (int nt = 0; nt < 4; ++nt)
                    acc[mt][nt] = __builtin_amdgcn_mfma_f32_16x16x32_bf16(
                        af[mt], bfr[nt], acc[mt][nt], 0, 0, 0);
        }
        __syncthreads();   // before next iteration overwrites LDS

        vcur = vnext;
    }

    // epilogue: nt innermost -> 4 consecutive 64B chunks per output row
    float bias[4];
    #pragma unroll
    for (int nt = 0; nt < 4; ++nt) {
        const int n = n0 + wn * 64 + nt * 16 + ml;
        bias[nt] = bx[n] + bt[n];
    }
    #pragma unroll
    for (int mt = 0; mt < 2; ++mt) {
        const int mb = m0 + wm * 32 + mt * 16 + q * 4;
        #pragma unroll
        for (int r = 0; r < 4; ++r) {
            float* orow = out + (size_t)(mb + r) * PP + n0 + wn * 64 + ml;
            #pragma unroll
            for (int nt = 0; nt < 4; ++nt)
                orow[nt * 16] = acc[mt][nt][r] + bias[nt];
        }
    }
}

// ---------------------------------------------------------------------------
extern "C" void kernel_launch(void* const* d_in, const int* in_sizes, int n_in,
                              void* d_out, int out_size, void* d_ws, size_t ws_size,
                              hipStream_t stream)
{
    const float* x   = (const float*)d_in[0];
    const float* tmv = (const float*)d_in[1];
    const float* w1v = (const float*)d_in[2];
    const float* b1v = (const float*)d_in[3];
    const float* w2v = (const float*)d_in[4];
    const float* w1t = (const float*)d_in[5];
    const float* b1t = (const float*)d_in[6];
    const float* w2t = (const float*)d_in[7];
    const float* wx  = (const float*)d_in[8];
    const float* bx  = (const float*)d_in[9];
    const float* wt  = (const float*)d_in[10];
    const float* bt  = (const float*)d_in[11];
    float* out = (float*)d_out;

    // ws: [0,1MB) BmatT bf16 [512][1024]
    unsigned short* Bws = (unsigned short*)d_ws;

    combine_kernel<<<256, 256, 0, stream>>>(w2v, w2t, wx, wt, Bws);
    gemm_fused_kernel<<<dim3(MM / 64, PP / 256), 512, 0, stream>>>(
        x, tmv, w1v, b1v, w1t, b1t, Bws, bx, bt, out);
}